// Round 1
// baseline (332.084 us; speedup 1.0000x reference)
//
#include <hip/hip_runtime.h>
#include <cstdint>
#include <cstddef>

typedef __attribute__((ext_vector_type(8))) __bf16 bf16x8;
typedef __attribute__((ext_vector_type(8))) unsigned short us8;
typedef __attribute__((ext_vector_type(4))) unsigned short us4;
typedef __attribute__((ext_vector_type(4))) float f32x4;

#define DEVI static __device__ __forceinline__

DEVI unsigned short f2bf(float f) {
  union { float f; unsigned u; } v; v.f = f;
  unsigned r = v.u + 0x7fffu + ((v.u >> 16) & 1u);
  return (unsigned short)(r >> 16);
}

DEVI f32x4 mfma16(us8 a, us8 b, f32x4 c) {
  return __builtin_amdgcn_mfma_f32_16x16x32_bf16(
      __builtin_bit_cast(bf16x8, a), __builtin_bit_cast(bf16x8, b), c, 0, 0, 0);
}

DEVI f32x4 fzero4() { f32x4 v = {0.f, 0.f, 0.f, 0.f}; return v; }

// ---------------------------------------------------------------------------
// Weight transpose + fp32->bf16 cast: w[K][N] -> wt[N][K]
// ---------------------------------------------------------------------------
__global__ __launch_bounds__(256)
void transpose_w(const float* __restrict__ w, unsigned short* __restrict__ wt,
                 int K, int N) {
  __shared__ unsigned short tile[64][65];
  const int t = threadIdx.x;
  const int kb = blockIdx.x * 64, nb = blockIdx.y * 64;
#pragma unroll
  for (int i = 0; i < 4; ++i) {
    int r = i * 16 + (t >> 4);
    int c = (t & 15) * 4;
    float4 v = *(const float4*)(w + (size_t)(kb + r) * N + nb + c);
    tile[r][c + 0] = f2bf(v.x);
    tile[r][c + 1] = f2bf(v.y);
    tile[r][c + 2] = f2bf(v.z);
    tile[r][c + 3] = f2bf(v.w);
  }
  __syncthreads();
#pragma unroll
  for (int i = 0; i < 4; ++i) {
    int n = i * 16 + (t >> 4);
    int k = (t & 15) * 4;
    us4 o;
    o[0] = tile[k + 0][n];
    o[1] = tile[k + 1][n];
    o[2] = tile[k + 2][n];
    o[3] = tile[k + 3][n];
    *(us4*)(wt + (size_t)(nb + n) * K + kb + k) = o;
  }
}

// ---------------------------------------------------------------------------
// LayerNorm over C=1024, fp32 in -> bf16 out. One block per row, 256 threads.
// ---------------------------------------------------------------------------
__global__ __launch_bounds__(256)
void ln_kernel(const float* __restrict__ x, const float* __restrict__ g,
               const float* __restrict__ b, unsigned short* __restrict__ o) {
  const int row = blockIdx.x;
  const int tid = threadIdx.x;
  const float* xr = x + (size_t)row * 1024;
  float4 v = *(const float4*)(xr + tid * 4);
  float s = v.x + v.y + v.z + v.w;
  float sq = v.x * v.x + v.y * v.y + v.z * v.z + v.w * v.w;
#pragma unroll
  for (int m = 1; m < 64; m <<= 1) {
    s += __shfl_xor(s, m, 64);
    sq += __shfl_xor(sq, m, 64);
  }
  __shared__ float ss[4], ssq[4];
  const int wid = tid >> 6, lane = tid & 63;
  if (lane == 0) { ss[wid] = s; ssq[wid] = sq; }
  __syncthreads();
  s = ss[0] + ss[1] + ss[2] + ss[3];
  sq = ssq[0] + ssq[1] + ssq[2] + ssq[3];
  const float mu = s * (1.f / 1024.f);
  const float var = sq * (1.f / 1024.f) - mu * mu;
  const float rstd = rsqrtf(var + 1e-5f);
  const int c = tid * 4;
  float4 gv = *(const float4*)(g + c);
  float4 bv = *(const float4*)(b + c);
  us4 ov;
  ov[0] = f2bf((v.x - mu) * rstd * gv.x + bv.x);
  ov[1] = f2bf((v.y - mu) * rstd * gv.y + bv.y);
  ov[2] = f2bf((v.z - mu) * rstd * gv.z + bv.z);
  ov[3] = f2bf((v.w - mu) * rstd * gv.w + bv.w);
  *(us4*)(o + (size_t)row * 1024 + c) = ov;
}

// ---------------------------------------------------------------------------
// DynamicPosBias MLP: 3969 rows, pd=64, out 16 heads -> posT[16][3969] (f32).
// One wave per row.
// ---------------------------------------------------------------------------
DEVI float pos_layer(float p, const float* __restrict__ g,
                     const float* __restrict__ be, const float* __restrict__ w,
                     const float* __restrict__ bb, int lane) {
  float s = p, sq = p * p;
#pragma unroll
  for (int m = 1; m < 64; m <<= 1) {
    s += __shfl_xor(s, m, 64);
    sq += __shfl_xor(sq, m, 64);
  }
  float mu = s * (1.f / 64.f);
  float var = sq * (1.f / 64.f) - mu * mu;
  float rstd = rsqrtf(var + 1e-5f);
  float y = fmaxf((p - mu) * rstd * g[lane] + be[lane], 0.f);
  float o = bb[lane];
  for (int k = 0; k < 64; ++k) {
    float yk = __shfl(y, k, 64);
    o += yk * w[k * 64 + lane];
  }
  return o;
}

__global__ __launch_bounds__(256)
void pos_mlp(const float* __restrict__ pp_w, const float* __restrict__ pp_b,
             const float* __restrict__ g1, const float* __restrict__ b1,
             const float* __restrict__ w1, const float* __restrict__ bb1,
             const float* __restrict__ g2, const float* __restrict__ b2,
             const float* __restrict__ w2, const float* __restrict__ bb2,
             const float* __restrict__ g3, const float* __restrict__ b3,
             const float* __restrict__ w3, const float* __restrict__ bb3,
             float* __restrict__ posT) {
  const int wid = threadIdx.x >> 6, lane = threadIdx.x & 63;
  const int row = blockIdx.x * 4 + wid;
  if (row >= 3969) return;
  const float bh = (float)(row / 63) - 31.f;
  const float bw = (float)(row % 63) - 31.f;
  float p = bh * pp_w[lane] + bw * pp_w[64 + lane] + pp_b[lane];
  p = pos_layer(p, g1, b1, w1, bb1, lane);
  p = pos_layer(p, g2, b2, w2, bb2, lane);
  // final layer: LN3 + relu + [64,16] proj
  float s = p, sq = p * p;
#pragma unroll
  for (int m = 1; m < 64; m <<= 1) {
    s += __shfl_xor(s, m, 64);
    sq += __shfl_xor(sq, m, 64);
  }
  float mu = s * (1.f / 64.f);
  float var = sq * (1.f / 64.f) - mu * mu;
  float rstd = rsqrtf(var + 1e-5f);
  float y = fmaxf((p - mu) * rstd * g3[lane] + b3[lane], 0.f);
  float o = 0.f;
  for (int k = 0; k < 64; ++k) {
    float yk = __shfl(y, k, 64);
    o += yk * w3[k * 16 + (lane & 15)];
  }
  if (lane < 16) posT[(size_t)lane * 3969 + row] = o + bb3[lane];
}

// ---------------------------------------------------------------------------
// GEMM: C[M,N] = A[M,K](bf16) @ Bt[N,K](bf16)^T, fp32 accum, fused epilogue.
// 128x128 tile, 4 waves of 64x64, BK=64, XOR-swizzled LDS, 2-barrier loop.
// ---------------------------------------------------------------------------
template <bool HAS_BIAS, bool GELU_, bool HAS_RES, bool OUT_BF16, bool OUT_F32>
__global__ __launch_bounds__(256)
void gemm_bt(const unsigned short* __restrict__ A,
             const unsigned short* __restrict__ Bt,
             const float* __restrict__ bias, const float* __restrict__ res,
             unsigned short* __restrict__ outb, float* __restrict__ outf,
             int M, int N, int K) {
  __shared__ unsigned short As[128 * 64];
  __shared__ unsigned short Bs[128 * 64];
  const int tid = threadIdx.x;
  const int lane = tid & 63;
  const int wid = tid >> 6;
  const int lr = lane & 15, lg = lane >> 4;
  const int wr = wid >> 1, wc = wid & 1;
  const int brow = blockIdx.x, bcol = blockIdx.y;

  f32x4 acc[4][4];
#pragma unroll
  for (int mt = 0; mt < 4; ++mt)
#pragma unroll
    for (int nt = 0; nt < 4; ++nt) acc[mt][nt] = fzero4();

  const int sr = tid >> 3;         // 0..31
  const int sc = (tid & 7) * 8;    // 0..56
  const unsigned short* Ag = A + (size_t)(brow * 128 + sr) * K + sc;
  const unsigned short* Bg = Bt + (size_t)(bcol * 128 + sr) * K + sc;

  const int nkb = K >> 6;
  for (int kb = 0; kb < nkb; ++kb) {
    us8 av[4], bv[4];
#pragma unroll
    for (int q2 = 0; q2 < 4; ++q2) {
      av[q2] = *(const us8*)(Ag + (size_t)(q2 * 32) * K + kb * 64);
      bv[q2] = *(const us8*)(Bg + (size_t)(q2 * 32) * K + kb * 64);
    }
    __syncthreads();
#pragma unroll
    for (int q2 = 0; q2 < 4; ++q2) {
      int r = q2 * 32 + sr;
      int off = r * 128 + ((sc * 2) ^ ((r & 7) << 4));
      *(us8*)((char*)As + off) = av[q2];
      *(us8*)((char*)Bs + off) = bv[q2];
    }
    __syncthreads();
#pragma unroll
    for (int ks = 0; ks < 2; ++ks) {
      us8 af[4], bfr[4];
#pragma unroll
      for (int mt = 0; mt < 4; ++mt) {
        int r = wr * 64 + mt * 16 + lr;
        af[mt] = *(const us8*)((const char*)As + r * 128 +
                               (((ks * 32 + lg * 8) * 2) ^ ((r & 7) << 4)));
      }
#pragma unroll
      for (int nt = 0; nt < 4; ++nt) {
        int r = wc * 64 + nt * 16 + lr;
        bfr[nt] = *(const us8*)((const char*)Bs + r * 128 +
                                (((ks * 32 + lg * 8) * 2) ^ ((r & 7) << 4)));
      }
#pragma unroll
      for (int mt = 0; mt < 4; ++mt)
#pragma unroll
        for (int nt = 0; nt < 4; ++nt)
          acc[mt][nt] = mfma16(af[mt], bfr[nt], acc[mt][nt]);
    }
  }

  // epilogue
#pragma unroll
  for (int mt = 0; mt < 4; ++mt) {
    const int row = brow * 128 + wr * 64 + mt * 16 + 4 * lg;
#pragma unroll
    for (int nt = 0; nt < 4; ++nt) {
      const int col = bcol * 128 + wc * 64 + nt * 16 + lr;
      float bsv = 0.f;
      if constexpr (HAS_BIAS) bsv = bias[col];
#pragma unroll
      for (int i = 0; i < 4; ++i) {
        float v = acc[mt][nt][i] + bsv;
        if constexpr (GELU_) v = 0.5f * v * (1.f + erff(v * 0.70710678118f));
        if constexpr (HAS_RES) v += res[(size_t)(row + i) * N + col];
        if constexpr (OUT_F32) outf[(size_t)(row + i) * N + col] = v;
        if constexpr (OUT_BF16) outb[(size_t)(row + i) * N + col] = f2bf(v);
      }
    }
  }
}

// ---------------------------------------------------------------------------
// Flash attention with dynamic relative-position bias.
// Grid: 4 (batch) * 16 (head) * 16 (q-block of 64 rows). 256 threads (4 waves,
// each owns 16 query rows). KV tiles of 64. MFMA 16x16x32 bf16.
// ---------------------------------------------------------------------------
__global__ __launch_bounds__(256)
void attn_kernel(const unsigned short* __restrict__ qb,
                 const unsigned short* __restrict__ kvb,
                 const float* __restrict__ posT,
                 unsigned short* __restrict__ attnb) {
  __shared__ unsigned short Ks[64 * 64];
  __shared__ unsigned short Vt[64 * 64];
  __shared__ unsigned short Ps[64 * 64];

  const int tid = threadIdx.x;
  const int wid = tid >> 6;
  const int lane = tid & 63;
  const int lr = lane & 15;
  const int lg = lane >> 4;

  const int bx = blockIdx.x;
  const int b = bx >> 8;
  const int h = (bx >> 4) & 15;
  const int qt = bx & 15;

  // Q fragments (held in registers for the whole KV loop)
  const int qrow = qt * 64 + wid * 16 + lr;
  const unsigned short* qg = qb + ((size_t)(b * 1024 + qrow)) * 1024 + h * 64;
  const us8 aq0 = *(const us8*)(qg + lg * 8);
  const us8 aq1 = *(const us8*)(qg + 32 + lg * 8);

  float mreg[4], lreg[4];
  f32x4 o[4];
#pragma unroll
  for (int i = 0; i < 4; ++i) { mreg[i] = -1e30f; lreg[i] = 0.f; }
#pragma unroll
  for (int t = 0; t < 4; ++t) o[t] = fzero4();

  const int sr = tid >> 2;        // 0..63 staging row (key index in tile)
  const int sc = (tid & 3) * 16;  // 0,16,32,48 (d offset)
  const float* pb = posT + (size_t)h * 3969;

  for (int kt = 0; kt < 16; ++kt) {
    __syncthreads();  // protect K/V LDS from previous iteration readers
    {
      const size_t rowoff =
          ((size_t)(b * 1024 + kt * 64 + sr)) * 2048 + h * 64 + sc;
      us8 k0 = *(const us8*)(kvb + rowoff);
      us8 k1 = *(const us8*)(kvb + rowoff + 8);
      us8 v0 = *(const us8*)(kvb + rowoff + 1024);
      us8 v1 = *(const us8*)(kvb + rowoff + 1024 + 8);
      char* ksb = (char*)Ks;
      const int swr = (sr & 7) << 4;
      *(us8*)(ksb + sr * 128 + ((sc * 2) ^ swr)) = k0;
      *(us8*)(ksb + sr * 128 + (((sc + 8) * 2) ^ swr)) = k1;
      char* vtb = (char*)Vt;
#pragma unroll
      for (int u = 0; u < 8; ++u) {
        int d0 = sc + u, d1 = sc + 8 + u;
        *(unsigned short*)(vtb + d0 * 128 + ((sr * 2) ^ ((d0 & 7) << 4))) = v0[u];
        *(unsigned short*)(vtb + d1 * 128 + ((sr * 2) ^ ((d1 & 7) << 4))) = v1[u];
      }
    }
    __syncthreads();

    // S = Q K^T
    f32x4 s[4];
#pragma unroll
    for (int nt = 0; nt < 4; ++nt) {
      f32x4 a = fzero4();
      const int kr = nt * 16 + lr;
      const char* ksb = (const char*)Ks;
      const int swz = (kr & 7) << 4;
      us8 bk0 = *(const us8*)(ksb + kr * 128 + (((lg * 8) * 2) ^ swz));
      us8 bk1 = *(const us8*)(ksb + kr * 128 + (((32 + lg * 8) * 2) ^ swz));
      a = mfma16(aq0, bk0, a);
      a = mfma16(aq1, bk1, a);
      s[nt] = a;
    }

    // scale + dynamic position bias; track per-row max
    float pm[4];
#pragma unroll
    for (int i = 0; i < 4; ++i) pm[i] = -1e30f;
#pragma unroll
    for (int nt = 0; nt < 4; ++nt) {
      const int kcol = kt * 64 + nt * 16 + lr;
      const int hj = kcol >> 5, wj = kcol & 31;
#pragma unroll
      for (int i = 0; i < 4; ++i) {
        const int qr = qt * 64 + wid * 16 + 4 * lg + i;
        const int hi = qr >> 5, wi = qr & 31;
        const int idx = (hi - hj + 31) * 63 + (wi - wj + 31);
        float sv = s[nt][i] * 0.125f + pb[idx];
        s[nt][i] = sv;
        pm[i] = fmaxf(pm[i], sv);
      }
    }
#pragma unroll
    for (int i = 0; i < 4; ++i) {
#pragma unroll
      for (int m = 1; m < 16; m <<= 1)
        pm[i] = fmaxf(pm[i], __shfl_xor(pm[i], m, 64));
    }

    // online softmax update
#pragma unroll
    for (int i = 0; i < 4; ++i) {
      const float mn = fmaxf(mreg[i], pm[i]);
      const float f = __expf(mreg[i] - mn);
      float acc = 0.f;
#pragma unroll
      for (int nt = 0; nt < 4; ++nt) {
        float e = __expf(s[nt][i] - mn);
        s[nt][i] = e;
        acc += e;
      }
#pragma unroll
      for (int m = 1; m < 16; m <<= 1) acc += __shfl_xor(acc, m, 64);
      lreg[i] = lreg[i] * f + acc;
#pragma unroll
      for (int t = 0; t < 4; ++t) o[t][i] *= f;
      mreg[i] = mn;
    }

    // P -> LDS (wave-private rows; no barrier needed), then PV
    {
      char* psb = (char*)Ps;
#pragma unroll
      for (int i = 0; i < 4; ++i) {
        const int prw = wid * 16 + 4 * lg + i;
        const int swz = (prw & 7) << 4;
#pragma unroll
        for (int nt = 0; nt < 4; ++nt) {
          *(unsigned short*)(psb + prw * 128 + (((nt * 16 + lr) * 2) ^ swz)) =
              f2bf(s[nt][i]);
        }
      }
      const int prow2 = wid * 16 + lr;
      const int swz2 = (prow2 & 7) << 4;
      us8 pa0 = *(const us8*)(psb + prow2 * 128 + (((lg * 8) * 2) ^ swz2));
      us8 pa1 = *(const us8*)(psb + prow2 * 128 + (((32 + lg * 8) * 2) ^ swz2));
      const char* vtb = (const char*)Vt;
#pragma unroll
      for (int t = 0; t < 4; ++t) {
        const int vr = t * 16 + lr;
        const int swv = (vr & 7) << 4;
        us8 pv0 = *(const us8*)(vtb + vr * 128 + (((lg * 8) * 2) ^ swv));
        us8 pv1 = *(const us8*)(vtb + vr * 128 + (((32 + lg * 8) * 2) ^ swv));
        o[t] = mfma16(pa0, pv0, o[t]);
        o[t] = mfma16(pa1, pv1, o[t]);
      }
    }
  }

  // normalize + store (bf16 for the proj GEMM)
#pragma unroll
  for (int t = 0; t < 4; ++t) {
#pragma unroll
    for (int i = 0; i < 4; ++i) {
      float v = o[t][i] / lreg[i];
      attnb[((size_t)(b * 1024 + qt * 64 + wid * 16 + 4 * lg + i)) * 1024 +
            h * 64 + t * 16 + lr] = f2bf(v);
    }
  }
}

// ---------------------------------------------------------------------------
// Launcher
// ---------------------------------------------------------------------------
extern "C" void kernel_launch(void* const* d_in, const int* in_sizes, int n_in,
                              void* d_out, int out_size, void* d_ws,
                              size_t ws_size, hipStream_t stream) {
  const float* x = (const float*)d_in[0];
  const float* n1g = (const float*)d_in[1];
  const float* n1b = (const float*)d_in[2];
  const float* q_w = (const float*)d_in[3];
  const float* kv_w = (const float*)d_in[4];
  const float* proj_w = (const float*)d_in[5];
  const float* proj_b = (const float*)d_in[6];
  const float* pp_w = (const float*)d_in[7];
  const float* pp_b = (const float*)d_in[8];
  const float* ln1g = (const float*)d_in[9];
  const float* ln1b = (const float*)d_in[10];
  const float* lin1w = (const float*)d_in[11];
  const float* lin1b = (const float*)d_in[12];
  const float* ln2g = (const float*)d_in[13];
  const float* ln2b = (const float*)d_in[14];
  const float* lin2w = (const float*)d_in[15];
  const float* lin2b = (const float*)d_in[16];
  const float* ln3g = (const float*)d_in[17];
  const float* ln3b = (const float*)d_in[18];
  const float* lin3w = (const float*)d_in[19];
  const float* lin3b = (const float*)d_in[20];
  const float* n2g = (const float*)d_in[21];
  const float* n2b = (const float*)d_in[22];
  const float* fc1_w = (const float*)d_in[23];
  const float* fc1_b = (const float*)d_in[24];
  const float* fc2_w = (const float*)d_in[25];
  const float* fc2_b = (const float*)d_in[26];
  float* out = (float*)d_out;

  char* ws = (char*)d_ws;
  const size_t MB = 1024ull * 1024ull;
  unsigned short* q_wT = (unsigned short*)(ws + 0 * MB);     // 2 MB
  unsigned short* kv_wT = (unsigned short*)(ws + 2 * MB);    // 4 MB
  unsigned short* proj_wT = (unsigned short*)(ws + 6 * MB);  // 2 MB
  unsigned short* fc1_wT = (unsigned short*)(ws + 8 * MB);   // 8 MB
  unsigned short* fc2_wT = (unsigned short*)(ws + 16 * MB);  // 8 MB
  unsigned short* xn = (unsigned short*)(ws + 24 * MB);      // 8 MB
  unsigned short* qbuf = (unsigned short*)(ws + 32 * MB);    // 8 MB
  unsigned short* kvbuf = (unsigned short*)(ws + 40 * MB);   // 16 MB
  unsigned short* attnb = (unsigned short*)(ws + 56 * MB);   // 8 MB
  float* x1 = (float*)(ws + 64 * MB);                        // 16 MB
  unsigned short* x2n = (unsigned short*)(ws + 80 * MB);     // 8 MB
  unsigned short* hb = (unsigned short*)(ws + 88 * MB);      // 32 MB
  float* posT = (float*)(ws + 120 * MB);                     // 254 KB

  // prep: weight transposes (fp32 -> bf16 [N][K])
  transpose_w<<<dim3(16, 16), 256, 0, stream>>>(q_w, q_wT, 1024, 1024);
  transpose_w<<<dim3(16, 32), 256, 0, stream>>>(kv_w, kv_wT, 1024, 2048);
  transpose_w<<<dim3(16, 16), 256, 0, stream>>>(proj_w, proj_wT, 1024, 1024);
  transpose_w<<<dim3(16, 64), 256, 0, stream>>>(fc1_w, fc1_wT, 1024, 4096);
  transpose_w<<<dim3(64, 16), 256, 0, stream>>>(fc2_w, fc2_wT, 4096, 1024);

  ln_kernel<<<4096, 256, 0, stream>>>(x, n1g, n1b, xn);
  pos_mlp<<<993, 256, 0, stream>>>(pp_w, pp_b, ln1g, ln1b, lin1w, lin1b, ln2g,
                                   ln2b, lin2w, lin2b, ln3g, ln3b, lin3w,
                                   lin3b, posT);

  // q / kv projections
  gemm_bt<false, false, false, true, false><<<dim3(32, 8), 256, 0, stream>>>(
      xn, q_wT, nullptr, nullptr, qbuf, nullptr, 4096, 1024, 1024);
  gemm_bt<false, false, false, true, false><<<dim3(32, 16), 256, 0, stream>>>(
      xn, kv_wT, nullptr, nullptr, kvbuf, nullptr, 4096, 2048, 1024);

  attn_kernel<<<1024, 256, 0, stream>>>(qbuf, kvbuf, posT, attnb);

  // proj + residual(x) -> x1 (fp32)
  gemm_bt<true, false, true, false, true><<<dim3(32, 8), 256, 0, stream>>>(
      attnb, proj_wT, proj_b, x, nullptr, x1, 4096, 1024, 1024);

  ln_kernel<<<4096, 256, 0, stream>>>(x1, n2g, n2b, x2n);

  // fc1 + bias + exact GELU -> hb (bf16)
  gemm_bt<true, true, false, true, false><<<dim3(32, 32), 256, 0, stream>>>(
      x2n, fc1_wT, fc1_b, nullptr, hb, nullptr, 4096, 4096, 1024);

  // fc2 + bias + residual(x1) -> out (fp32)
  gemm_bt<true, false, true, false, true><<<dim3(32, 8), 256, 0, stream>>>(
      hb, fc2_wT, fc2_b, x1, nullptr, out, 4096, 1024, 4096);

  (void)in_sizes; (void)n_in; (void)out_size; (void)ws_size;
}